// Round 16
// baseline (327.058 us; speedup 1.0000x reference)
//
#include <hip/hip_runtime.h>
#include <hip/hip_bf16.h>
#include <stdint.h>
#include <math.h>

typedef __attribute__((ext_vector_type(8))) short bf16x8;
typedef __attribute__((ext_vector_type(4))) float f32x4;

#define D_K 256
#define JCHUNK 2048
#define SB 256              // superblock j-width (phase alternation unit)
#define NSB (JCHUNK / SB)   // 8
#define BT 32               // MFMA subtile j-width (staged tile rows)
#define NST (SB / BT)       // 8 subtiles per superblock

__device__ __forceinline__ unsigned short f2bf(float f) {
    unsigned u = __float_as_uint(f);
    u += 0x7fffu + ((u >> 16) & 1u);   // round-to-nearest-even
    return (unsigned short)(u >> 16);
}
__device__ __forceinline__ float bf2f(unsigned short u) {
    return __uint_as_float(((unsigned)u) << 16);
}
__device__ __forceinline__ void gload_lds16(const void* g, void* l) {
    __builtin_amdgcn_global_load_lds(
        (const __attribute__((address_space(1))) void*)g,
        (__attribute__((address_space(3))) void*)l,
        16, 0, 0);
}

// ---------------- Kernel 1: row-normalize z -> bf16; zero partials ----------------
__global__ void normalize_k(const float* __restrict__ z,
                            unsigned short* __restrict__ zn,
                            float* __restrict__ part, int N) {
    int gid  = blockIdx.x * blockDim.x + threadIdx.x;
    if (gid < 5 * N) part[gid] = 0.f;      // stream-ordered before fused_k
    int gw   = gid >> 6;                   // one wave per row
    int lane = threadIdx.x & 63;
    if (gw >= N) return;
    float4 v = reinterpret_cast<const float4*>(z + (size_t)gw * D_K)[lane];
    float ss = v.x * v.x + v.y * v.y + v.z * v.z + v.w * v.w;
#pragma unroll
    for (int m = 32; m; m >>= 1) ss += __shfl_xor(ss, m);
    float sc = 1.0f / fmaxf(sqrtf(ss), 1e-8f);
    ushort4 o;
    o.x = f2bf(v.x * sc); o.y = f2bf(v.y * sc);
    o.z = f2bf(v.z * sc); o.w = f2bf(v.w * sc);
    reinterpret_cast<ushort4*>(zn + (size_t)gw * D_K)[lane] = o;
}

// Stage one 32-row x 256-d bf16 zn tile (16 KB) into LDS in [kslot][row][16B]
// layout (R6-proven: 0 bank conflicts). gload_lds dest linear; remap on source.
__device__ __forceinline__ void stage_zn(char* dst, const unsigned short* zn,
                                         int j0, int tid, int wid) {
#pragma unroll
    for (int it = 0; it < 4; ++it) {
        int li    = it * 4096 + tid * 16;
        int kslot = li >> 9;          // 0..31
        int row   = (li >> 4) & 31;   // 0..31
        const char* src = reinterpret_cast<const char*>(zn) +
                          ((size_t)(j0 + row) << 9) + (size_t)kslot * 16;
        gload_lds16(src, dst + it * 4096 + wid * 1024);
    }
}

// ---------------- Kernel 2: two-phase fused kernel (R9 exact, best measured) -------
__global__ __launch_bounds__(256, 2) void fused_k(
    const unsigned short* __restrict__ zn,
    const float* __restrict__ adj,
    const float* __restrict__ tsim,
    float* __restrict__ part, int N) {
    __shared__ alignas(128) char stageL[2][BT * 512];   // 2 x 16 KB
    __shared__ alignas(128) char parkL[4][16 * 512];    // 4 waves x 8 KB bf16 park

    const float INV_T = 1.0f / 0.07f;
    const int NIB = N >> 6;
    int ib  = blockIdx.x & (NIB - 1);
    int jc  = blockIdx.x / NIB;            // 0..3
    int tid = threadIdx.x;
    int wid = tid >> 6, lane = tid & 63;
    int l15 = lane & 15, lhi = lane >> 4;
    int i0w = ib * 64 + wid * 16;          // this wave's 16 i-rows
    int gi  = i0w + l15;                   // phase-1 output col = i-row
    int jb  = jc * JCHUNK;
    char* parkW = parkL[wid];

    // B-operand fragments: zn row gi in registers for whole kernel (32 VGPRs)
    bf16x8 bfr[8];
    {
        const bf16x8* bp = reinterpret_cast<const bf16x8*>(zn + (size_t)gi * D_K) + lhi;
#pragma unroll
        for (int ks = 0; ks < 8; ++ks) bfr[ks] = bp[ks * 4];
    }

    float accden = 0.f;                       // den partial for i-row gi
    float s1p[4] = {0.f, 0.f, 0.f, 0.f};      // phase-2 partials, row rg*4+lhi
    float app[4] = {0.f, 0.f, 0.f, 0.f};
    float t1p[4] = {0.f, 0.f, 0.f, 0.f};
    float ttp[4] = {0.f, 0.f, 0.f, 0.f};

    // prologue: stage first subtile
    stage_zn(stageL[0], zn, jb, tid, wid);
    asm volatile("s_waitcnt vmcnt(0)" ::: "memory");
    __syncthreads();
    int cur = 0;

    for (int sb = 0; sb < NSB; ++sb) {
        int jsb = jb + sb * SB;

        // ---------- phase 1: sim for 64 i x 256 j (this wave: 16 i) ----------
        for (int st = 0; st < NST; ++st) {
            int nj = jsb + (st + 1) * BT;          // next within sb, or next sb start
            if (sb + 1 < NSB || st + 1 < NST)
                stage_zn(stageL[cur ^ 1], zn, nj, tid, wid);

            const char* buf = stageL[cur];
            f32x4 acc[2] = {(f32x4){0.f,0.f,0.f,0.f}, (f32x4){0.f,0.f,0.f,0.f}};
#pragma unroll
            for (int ks = 0; ks < 8; ++ks) {
#pragma unroll
                for (int t = 0; t < 2; ++t) {
                    int boff = (ks << 11) + (lhi << 9) + (t << 8) + (l15 << 4);
                    bf16x8 aj = *reinterpret_cast<const bf16x8*>(buf + boff);
                    acc[t] = __builtin_amdgcn_mfma_f32_16x16x32_bf16(aj, bfr[ks], acc[t], 0, 0, 0);
                }
            }
#pragma unroll
            for (int t = 0; t < 2; ++t) {
                int jcol = st * BT + t * 16 + lhi * 4;   // j within superblock
                float sv[4];
#pragma unroll
                for (int r = 0; r < 4; ++r) {
                    sv[r] = acc[t][r] * INV_T;
                    accden += (gi == jsb + jcol + r) ? 0.f : __expf(sv[r]);
                }
                ushort4 pk;
                pk.x = f2bf(sv[0]); pk.y = f2bf(sv[1]);
                pk.z = f2bf(sv[2]); pk.w = f2bf(sv[3]);
                *reinterpret_cast<ushort4*>(
                    parkW + l15 * 512 + ((jcol * 2) ^ ((l15 & 7) << 4))) = pk;
            }
            asm volatile("s_waitcnt vmcnt(0)" ::: "memory");
            __syncthreads();
            cur ^= 1;
        }

        // ---------- phase 2: stream adj/tsim, dot vs parked sim ----------
#pragma unroll
        for (int rg = 0; rg < 4; ++rg) {
            int irow = rg * 4 + lhi;
            const float* ar = adj  + (size_t)(i0w + irow) * N + jsb + l15 * 8;
            const float* tr = tsim + (size_t)(i0w + irow) * N + jsb + l15 * 8;
            const char*  pr = parkW + irow * 512;
            int sx = (irow & 7) << 4;
#pragma unroll
            for (int q = 0; q < 2; ++q) {
                f32x4 a0 = __builtin_nontemporal_load(
                    reinterpret_cast<const f32x4*>(ar + q * 128));
                f32x4 a1 = __builtin_nontemporal_load(
                    reinterpret_cast<const f32x4*>(ar + q * 128 + 4));
                f32x4 t0 = __builtin_nontemporal_load(
                    reinterpret_cast<const f32x4*>(tr + q * 128));
                f32x4 t1 = __builtin_nontemporal_load(
                    reinterpret_cast<const f32x4*>(tr + q * 128 + 4));
                bf16x8 s8 = *reinterpret_cast<const bf16x8*>(
                    pr + ((l15 * 16 + q * 256) ^ sx));
                float s[8];
#pragma unroll
                for (int e = 0; e < 8; ++e) s[e] = bf2f((unsigned short)s8[e]);
                float s1 = s1p[rg], t1v = t1p[rg];
#pragma unroll
                for (int e = 0; e < 4; ++e) {
                    s1  = fmaf(a0[e], s[e], s1);
                    s1  = fmaf(a1[e], s[4 + e], s1);
                    t1v = fmaf(t0[e], s[e], t1v);
                    t1v = fmaf(t1[e], s[4 + e], t1v);
                }
                s1p[rg] = s1; t1p[rg] = t1v;
                app[rg] += (a0[0] + a0[1] + a0[2] + a0[3]) +
                           (a1[0] + a1[1] + a1[2] + a1[3]);
                ttp[rg] += (t0[0] + t0[1] + t0[2] + t0[3]) +
                           (t1[0] + t1[1] + t1[2] + t1[3]);
            }
        }
    }

    // ---------- final reductions + atomics ----------
    accden += __shfl_xor(accden, 16); accden += __shfl_xor(accden, 32);
    if (lhi == 0) atomicAdd(part + gi, accden);
#pragma unroll
    for (int rg = 0; rg < 4; ++rg) {
        float s = s1p[rg], a = app[rg], u = t1p[rg], w = ttp[rg];
#pragma unroll
        for (int m = 1; m < 16; m <<= 1) {
            s += __shfl_xor(s, m); a += __shfl_xor(a, m);
            u += __shfl_xor(u, m); w += __shfl_xor(w, m);
        }
        if (l15 == 0) {
            int gr = i0w + rg * 4 + lhi;
            atomicAdd(part + (size_t)N + gr, s);
            atomicAdd(part + (size_t)2 * N + gr, a);
            atomicAdd(part + (size_t)3 * N + gr, u);
            atomicAdd(part + (size_t)4 * N + gr, w);
        }
    }
}

// ---------------- Kernel 3: finalize scalar ----------------
__global__ void finalize_k(const float* __restrict__ part, float* __restrict__ out, int N) {
    const float* den = part;
    const float* s1  = part + (size_t)N;
    const float* aa  = part + (size_t)2 * N;
    const float* t1  = part + (size_t)3 * N;
    const float* tt  = part + (size_t)4 * N;
    float acc = 0.f;
    for (int i = threadIdx.x; i < N; i += blockDim.x) {
        float ld = logf(den[i] + 1e-8f);
        acc += -(s1[i] - ld * aa[i]) / (aa[i] + 1e-8f)
               - (t1[i] - ld * tt[i]) / (tt[i] + 1e-8f);
    }
#pragma unroll
    for (int m = 32; m; m >>= 1) acc += __shfl_xor(acc, m);
    __shared__ float red[16];
    if ((threadIdx.x & 63) == 0) red[threadIdx.x >> 6] = acc;
    __syncthreads();
    if (threadIdx.x == 0) {
        float tot = 0.f;
        int nw = blockDim.x >> 6;
        for (int w = 0; w < nw; ++w) tot += red[w];
        out[0] = tot / (float)N;
    }
}

// =============== PROBES: identical 256MB footprint, run-length sweep ===============
// All read even 64-row bands, adj+tsim. Load-only, asm-kept-live.

// P1: fully contiguous — block reads one 512KB sequential slice.
__global__ __launch_bounds__(256) void p_contig_k(const float* __restrict__ adj,
                                                  const float* __restrict__ tsim, int N) {
    const float* src = (blockIdx.x & 1) ? tsim : adj;
    int slot = blockIdx.x >> 1;            // 0..255
    int band = slot >> 2;                  // 0..63
    int sub  = slot & 3;
    const float* base = src + (size_t)(band * 128) * N + (size_t)sub * 131072;
    int tid = threadIdx.x;
    f32x4 s = {0, 0, 0, 0};
    for (int it = 0; it < 128; it += 8) {
        f32x4 v[8];
#pragma unroll
        for (int u = 0; u < 8; ++u)
            v[u] = *reinterpret_cast<const f32x4*>(base + (size_t)(it + u) * 1024 + tid * 4);
#pragma unroll
        for (int u = 0; u < 8; ++u) s += v[u];
    }
    float r = s[0] + s[1] + s[2] + s[3];
    asm volatile("" :: "v"(r));
}

// P2: 1KB per row-visit (full wave on one row) — R14-phase-2 shape.
__global__ __launch_bounds__(256) void p_pat1k_k(const float* __restrict__ adj,
                                                 const float* __restrict__ tsim, int N) {
    int ib = (blockIdx.x & 63) * 2;
    int jc = blockIdx.x >> 6;              // 0..7
    int tid = threadIdx.x;
    int wid = tid >> 6, lane = tid & 63;
    int i0w = ib * 64 + wid * 16;
    const float* ab = adj  + (size_t)i0w * N + jc * 1024 + lane * 4;
    const float* tb = tsim + (size_t)i0w * N + jc * 1024 + lane * 4;
    f32x4 s = {0, 0, 0, 0};
    for (int r = 0; r < 16; r += 2) {
        f32x4 v[16];
#pragma unroll
        for (int u = 0; u < 2; ++u) {
            const float* a = ab + (size_t)(r + u) * N;
            const float* t = tb + (size_t)(r + u) * N;
#pragma unroll
            for (int q = 0; q < 4; ++q) {
                v[u * 8 + q]     = *reinterpret_cast<const f32x4*>(a + q * 256);
                v[u * 8 + 4 + q] = *reinterpret_cast<const f32x4*>(t + q * 256);
            }
        }
#pragma unroll
        for (int u = 0; u < 16; ++u) s += v[u];
    }
    float r2 = s[0] + s[1] + s[2] + s[3];
    asm volatile("" :: "v"(r2));
}

// P3: 512B per row-visit (half-wave per row, 2 rows per instruction).
__global__ __launch_bounds__(256) void p_pat512_k(const float* __restrict__ adj,
                                                  const float* __restrict__ tsim, int N) {
    int ib = (blockIdx.x & 63) * 2;
    int jc = blockIdx.x >> 6;
    int tid = threadIdx.x;
    int wid = tid >> 6, lane = tid & 63;
    int i0w = ib * 64 + wid * 16;
    int rh  = lane >> 5;
    int l32 = lane & 31;
    const float* ab = adj  + (size_t)(i0w + rh) * N + jc * 1024 + l32 * 4;
    const float* tb = tsim + (size_t)(i0w + rh) * N + jc * 1024 + l32 * 4;
    f32x4 s = {0, 0, 0, 0};
    for (int r = 0; r < 16; r += 2) {
        f32x4 v[16];
#pragma unroll
        for (int q = 0; q < 8; ++q) {
            v[q]     = *reinterpret_cast<const f32x4*>(ab + (size_t)r * N + q * 128);
            v[8 + q] = *reinterpret_cast<const f32x4*>(tb + (size_t)r * N + q * 128);
        }
#pragma unroll
        for (int u = 0; u < 16; ++u) s += v[u];
    }
    float r2 = s[0] + s[1] + s[2] + s[3];
    asm volatile("" :: "v"(r2));
}

// P4: 128B per row-visit (16 rows per instruction) — R6/D1 shape, control.
__global__ __launch_bounds__(256) void p_pat128_k(const float* __restrict__ adj,
                                                  const float* __restrict__ tsim, int N) {
    int ib = (blockIdx.x & 63) * 2;
    int jc = blockIdx.x >> 6;
    int tid = threadIdx.x;
    int wid = tid >> 6, lane = tid & 63;
    int l15 = lane & 15, lhi = lane >> 4;
    int gi  = ib * 64 + wid * 16 + l15;
    const float* ab = adj  + (size_t)gi * N + jc * 1024 + lhi * 4;
    const float* tb = tsim + (size_t)gi * N + jc * 1024 + lhi * 4;
    f32x4 s0 = {0,0,0,0}, s1 = {0,0,0,0};
    for (int jt = 0; jt < 32; jt += 4) {
        f32x4 v[16];
#pragma unroll
        for (int u = 0; u < 4; ++u) {
            const float* a = ab + (jt + u) * 32;
            const float* t = tb + (jt + u) * 32;
            v[u*4+0] = *reinterpret_cast<const f32x4*>(a);
            v[u*4+1] = *reinterpret_cast<const f32x4*>(a + 16);
            v[u*4+2] = *reinterpret_cast<const f32x4*>(t);
            v[u*4+3] = *reinterpret_cast<const f32x4*>(t + 16);
        }
#pragma unroll
        for (int u = 0; u < 8; ++u) { s0 += v[u]; s1 += v[8 + u]; }
    }
    f32x4 s = s0 + s1;
    float r = s[0] + s[1] + s[2] + s[3];
    asm volatile("" :: "v"(r));
}

extern "C" void kernel_launch(void* const* d_in, const int* in_sizes, int n_in,
                              void* d_out, int out_size, void* d_ws, size_t ws_size,
                              hipStream_t stream) {
    const float* z    = (const float*)d_in[0];
    const float* adj  = (const float*)d_in[1];
    const float* tsim = (const float*)d_in[2];

    int N = (int)(sqrt((double)in_sizes[1]) + 0.5);  // 8192

    unsigned short* zn = (unsigned short*)d_ws;                   // 4 MB
    float* part = (float*)((char*)d_ws + (size_t)N * D_K * 2);    // 5*N f32

    normalize_k<<<N / 4, 256, 0, stream>>>(z, zn, part, N);

    int nblocks = (N >> 6) * (N / JCHUNK);  // 128 * 4 = 512
    fused_k<<<nblocks, 256, 0, stream>>>(zn, adj, tsim, part, N);

    finalize_k<<<1, 1024, 0, stream>>>(part, (float*)d_out, N);

    // ---- run-length probe matrix (output-neutral; read from profile) ----
    p_contig_k<<<512, 256, 0, stream>>>(adj, tsim, N);
    p_pat1k_k <<<512, 256, 0, stream>>>(adj, tsim, N);
    p_pat512_k<<<512, 256, 0, stream>>>(adj, tsim, N);
    p_pat128_k<<<512, 256, 0, stream>>>(adj, tsim, N);
}

// Round 17
// 164.587 us; speedup vs baseline: 1.9871x; 1.9871x over previous
//
#include <hip/hip_runtime.h>
#include <hip/hip_bf16.h>
#include <stdint.h>
#include <math.h>

typedef __attribute__((ext_vector_type(8))) short bf16x8;
typedef __attribute__((ext_vector_type(4))) float f32x4;

#define D_K 256
#define JCHUNK 2048
#define SB 256              // superblock j-width (phase alternation unit)
#define NSB (JCHUNK / SB)   // 8
#define BT 32               // MFMA subtile j-width (staged tile rows)
#define NST (SB / BT)       // 8 subtiles per superblock

__device__ __forceinline__ unsigned short f2bf(float f) {
    unsigned u = __float_as_uint(f);
    u += 0x7fffu + ((u >> 16) & 1u);   // round-to-nearest-even
    return (unsigned short)(u >> 16);
}
__device__ __forceinline__ float bf2f(unsigned short u) {
    return __uint_as_float(((unsigned)u) << 16);
}
__device__ __forceinline__ void gload_lds16(const void* g, void* l) {
    __builtin_amdgcn_global_load_lds(
        (const __attribute__((address_space(1))) void*)g,
        (__attribute__((address_space(3))) void*)l,
        16, 0, 0);
}

// ---------------- Kernel 1: row-normalize z -> bf16; zero partials ----------------
__global__ void normalize_k(const float* __restrict__ z,
                            unsigned short* __restrict__ zn,
                            float* __restrict__ part, int N) {
    int gid  = blockIdx.x * blockDim.x + threadIdx.x;
    if (gid < 5 * N) part[gid] = 0.f;      // stream-ordered before fused_k
    int gw   = gid >> 6;                   // one wave per row
    int lane = threadIdx.x & 63;
    if (gw >= N) return;
    float4 v = reinterpret_cast<const float4*>(z + (size_t)gw * D_K)[lane];
    float ss = v.x * v.x + v.y * v.y + v.z * v.z + v.w * v.w;
#pragma unroll
    for (int m = 32; m; m >>= 1) ss += __shfl_xor(ss, m);
    float sc = 1.0f / fmaxf(sqrtf(ss), 1e-8f);
    ushort4 o;
    o.x = f2bf(v.x * sc); o.y = f2bf(v.y * sc);
    o.z = f2bf(v.z * sc); o.w = f2bf(v.w * sc);
    reinterpret_cast<ushort4*>(zn + (size_t)gw * D_K)[lane] = o;
}

// Stage one 32-row x 256-d bf16 zn tile (16 KB) into LDS in [kslot][row][16B]
// layout (R6-proven: 0 bank conflicts). gload_lds dest linear; remap on source.
__device__ __forceinline__ void stage_zn(char* dst, const unsigned short* zn,
                                         int j0, int tid, int wid) {
#pragma unroll
    for (int it = 0; it < 4; ++it) {
        int li    = it * 4096 + tid * 16;
        int kslot = li >> 9;          // 0..31
        int row   = (li >> 4) & 31;   // 0..31
        const char* src = reinterpret_cast<const char*>(zn) +
                          ((size_t)(j0 + row) << 9) + (size_t)kslot * 16;
        gload_lds16(src, dst + it * 4096 + wid * 1024);
    }
}

// ---------------- Kernel 2: two-phase fused kernel (R9 structure) ----------------
// ONLY change vs R9/R16: dispatch geometry. jc is FAST-varying in blockIdx and
// each block rotates its superblock order by sb0 = ib & 7. Co-resident blocks
// (all 512, 2/CU) then cover ALL 32 distinct 1KB offsets (mod 32KB row stride)
// uniformly at every lockstep stage -> HBM channel load spread, instead of 4
// offsets hammering ~1/8 of the channels (the theory for the 1.7 TB/s pin).
// part: [0,N) den | [N,2N) S1 | [2N,3N) A | [3N,4N) T1 | [4N,5N) T
__global__ __launch_bounds__(256, 2) void fused_k(
    const unsigned short* __restrict__ zn,
    const float* __restrict__ adj,
    const float* __restrict__ tsim,
    float* __restrict__ part, int N) {
    __shared__ alignas(128) char stageL[2][BT * 512];   // 2 x 16 KB
    __shared__ alignas(128) char parkL[4][16 * 512];    // 4 waves x 8 KB bf16 park

    const float INV_T = 1.0f / 0.07f;
    const int NIB = N >> 6;
    int ib  = (blockIdx.x >> 2) & (NIB - 1);   // 0..127 (slow-varying)
    int jc  = blockIdx.x & 3;                  // 0..3  (FAST-varying)
    int sb0 = ib & (NSB - 1);                  // per-block superblock rotation
    int tid = threadIdx.x;
    int wid = tid >> 6, lane = tid & 63;
    int l15 = lane & 15, lhi = lane >> 4;
    int i0w = ib * 64 + wid * 16;          // this wave's 16 i-rows
    int gi  = i0w + l15;                   // phase-1 output col = i-row
    int jb  = jc * JCHUNK;
    char* parkW = parkL[wid];

    // B-operand fragments: zn row gi in registers for whole kernel (32 VGPRs)
    bf16x8 bfr[8];
    {
        const bf16x8* bp = reinterpret_cast<const bf16x8*>(zn + (size_t)gi * D_K) + lhi;
#pragma unroll
        for (int ks = 0; ks < 8; ++ks) bfr[ks] = bp[ks * 4];
    }

    float accden = 0.f;                       // den partial for i-row gi
    float s1p[4] = {0.f, 0.f, 0.f, 0.f};      // phase-2 partials, row rg*4+lhi
    float app[4] = {0.f, 0.f, 0.f, 0.f};
    float t1p[4] = {0.f, 0.f, 0.f, 0.f};
    float ttp[4] = {0.f, 0.f, 0.f, 0.f};

    // prologue: stage first subtile of the ROTATED first superblock
    stage_zn(stageL[0], zn, jb + sb0 * SB, tid, wid);
    asm volatile("s_waitcnt vmcnt(0)" ::: "memory");
    __syncthreads();
    int cur = 0;

    for (int s = 0; s < NSB; ++s) {
        int sbi = (sb0 + s) & (NSB - 1);
        int jsb = jb + sbi * SB;

        // ---------- phase 1: sim for 64 i x 256 j (this wave: 16 i) ----------
        for (int st = 0; st < NST; ++st) {
            // issue next stage: st+1 within superblock, else first subtile of
            // the NEXT (rotated) superblock
            if (st + 1 < NST) {
                stage_zn(stageL[cur ^ 1], zn, jsb + (st + 1) * BT, tid, wid);
            } else if (s + 1 < NSB) {
                int nsb = (sb0 + s + 1) & (NSB - 1);
                stage_zn(stageL[cur ^ 1], zn, jb + nsb * SB, tid, wid);
            }

            const char* buf = stageL[cur];
            f32x4 acc[2] = {(f32x4){0.f,0.f,0.f,0.f}, (f32x4){0.f,0.f,0.f,0.f}};
#pragma unroll
            for (int ks = 0; ks < 8; ++ks) {
#pragma unroll
                for (int t = 0; t < 2; ++t) {
                    int boff = (ks << 11) + (lhi << 9) + (t << 8) + (l15 << 4);
                    bf16x8 aj = *reinterpret_cast<const bf16x8*>(buf + boff);
                    acc[t] = __builtin_amdgcn_mfma_f32_16x16x32_bf16(aj, bfr[ks], acc[t], 0, 0, 0);
                }
            }
#pragma unroll
            for (int t = 0; t < 2; ++t) {
                int jcol = st * BT + t * 16 + lhi * 4;   // j within superblock
                float sv[4];
#pragma unroll
                for (int r = 0; r < 4; ++r) {
                    sv[r] = acc[t][r] * INV_T;
                    accden += (gi == jsb + jcol + r) ? 0.f : __expf(sv[r]);
                }
                ushort4 pk;
                pk.x = f2bf(sv[0]); pk.y = f2bf(sv[1]);
                pk.z = f2bf(sv[2]); pk.w = f2bf(sv[3]);
                *reinterpret_cast<ushort4*>(
                    parkW + l15 * 512 + ((jcol * 2) ^ ((l15 & 7) << 4))) = pk;
            }
            asm volatile("s_waitcnt vmcnt(0)" ::: "memory");
            __syncthreads();
            cur ^= 1;
        }

        // ---------- phase 2: stream adj/tsim, dot vs parked sim ----------
#pragma unroll
        for (int rg = 0; rg < 4; ++rg) {
            int irow = rg * 4 + lhi;
            const float* ar = adj  + (size_t)(i0w + irow) * N + jsb + l15 * 8;
            const float* tr = tsim + (size_t)(i0w + irow) * N + jsb + l15 * 8;
            const char*  pr = parkW + irow * 512;
            int sx = (irow & 7) << 4;
#pragma unroll
            for (int q = 0; q < 2; ++q) {
                f32x4 a0 = __builtin_nontemporal_load(
                    reinterpret_cast<const f32x4*>(ar + q * 128));
                f32x4 a1 = __builtin_nontemporal_load(
                    reinterpret_cast<const f32x4*>(ar + q * 128 + 4));
                f32x4 t0 = __builtin_nontemporal_load(
                    reinterpret_cast<const f32x4*>(tr + q * 128));
                f32x4 t1 = __builtin_nontemporal_load(
                    reinterpret_cast<const f32x4*>(tr + q * 128 + 4));
                bf16x8 s8 = *reinterpret_cast<const bf16x8*>(
                    pr + ((l15 * 16 + q * 256) ^ sx));
                float s[8];
#pragma unroll
                for (int e = 0; e < 8; ++e) s[e] = bf2f((unsigned short)s8[e]);
                float s1 = s1p[rg], t1v = t1p[rg];
#pragma unroll
                for (int e = 0; e < 4; ++e) {
                    s1  = fmaf(a0[e], s[e], s1);
                    s1  = fmaf(a1[e], s[4 + e], s1);
                    t1v = fmaf(t0[e], s[e], t1v);
                    t1v = fmaf(t1[e], s[4 + e], t1v);
                }
                s1p[rg] = s1; t1p[rg] = t1v;
                app[rg] += (a0[0] + a0[1] + a0[2] + a0[3]) +
                           (a1[0] + a1[1] + a1[2] + a1[3]);
                ttp[rg] += (t0[0] + t0[1] + t0[2] + t0[3]) +
                           (t1[0] + t1[1] + t1[2] + t1[3]);
            }
        }
    }

    // ---------- final reductions + atomics ----------
    accden += __shfl_xor(accden, 16); accden += __shfl_xor(accden, 32);
    if (lhi == 0) atomicAdd(part + gi, accden);
#pragma unroll
    for (int rg = 0; rg < 4; ++rg) {
        float s = s1p[rg], a = app[rg], u = t1p[rg], w = ttp[rg];
#pragma unroll
        for (int m = 1; m < 16; m <<= 1) {
            s += __shfl_xor(s, m); a += __shfl_xor(a, m);
            u += __shfl_xor(u, m); w += __shfl_xor(w, m);
        }
        if (l15 == 0) {
            int gr = i0w + rg * 4 + lhi;
            atomicAdd(part + (size_t)N + gr, s);
            atomicAdd(part + (size_t)2 * N + gr, a);
            atomicAdd(part + (size_t)3 * N + gr, u);
            atomicAdd(part + (size_t)4 * N + gr, w);
        }
    }
}

// ---------------- Kernel 3: finalize scalar ----------------
__global__ void finalize_k(const float* __restrict__ part, float* __restrict__ out, int N) {
    const float* den = part;
    const float* s1  = part + (size_t)N;
    const float* aa  = part + (size_t)2 * N;
    const float* t1  = part + (size_t)3 * N;
    const float* tt  = part + (size_t)4 * N;
    float acc = 0.f;
    for (int i = threadIdx.x; i < N; i += blockDim.x) {
        float ld = logf(den[i] + 1e-8f);
        acc += -(s1[i] - ld * aa[i]) / (aa[i] + 1e-8f)
               - (t1[i] - ld * tt[i]) / (tt[i] + 1e-8f);
    }
#pragma unroll
    for (int m = 32; m; m >>= 1) acc += __shfl_xor(acc, m);
    __shared__ float red[16];
    if ((threadIdx.x & 63) == 0) red[threadIdx.x >> 6] = acc;
    __syncthreads();
    if (threadIdx.x == 0) {
        float tot = 0.f;
        int nw = blockDim.x >> 6;
        for (int w = 0; w < nw; ++w) tot += red[w];
        out[0] = tot / (float)N;
    }
}

extern "C" void kernel_launch(void* const* d_in, const int* in_sizes, int n_in,
                              void* d_out, int out_size, void* d_ws, size_t ws_size,
                              hipStream_t stream) {
    const float* z    = (const float*)d_in[0];
    const float* adj  = (const float*)d_in[1];
    const float* tsim = (const float*)d_in[2];

    int N = (int)(sqrt((double)in_sizes[1]) + 0.5);  // 8192

    unsigned short* zn = (unsigned short*)d_ws;                   // 4 MB
    float* part = (float*)((char*)d_ws + (size_t)N * D_K * 2);    // 5*N f32

    normalize_k<<<N / 4, 256, 0, stream>>>(z, zn, part, N);

    int nblocks = (N >> 6) * (N / JCHUNK);  // 128 * 4 = 512
    fused_k<<<nblocks, 256, 0, stream>>>(zn, adj, tsim, part, N);

    finalize_k<<<1, 1024, 0, stream>>>(part, (float*)d_out, N);
}